// Round 12
// baseline (390.035 us; speedup 1.0000x reference)
//
#include <hip/hip_runtime.h>
#include <stdint.h>

#define DIM   1024
#define INTER 2048
#define NEXP  8
#define TIMAX 136   // max active 128-row tiles: 16384/128 + 7 experts' rounding, rounded to /4

typedef _Float16 f16;
typedef __attribute__((ext_vector_type(2))) _Float16 f16x2;
typedef __attribute__((ext_vector_type(4))) _Float16 f16x4;
typedef __attribute__((ext_vector_type(8))) _Float16 f16x8;
typedef __attribute__((ext_vector_type(4))) float    f32x4;

// ---------------- async global->LDS (16B per lane) ----------------
static __device__ __forceinline__ void gload16(const void* gsrc, void* lds) {
    __builtin_amdgcn_global_load_lds(
        (const __attribute__((address_space(1))) uint32_t*)gsrc,
        (__attribute__((address_space(3))) uint32_t*)lds,
        16, 0, 0);
}

// ---------------- fused gate (sigmoid top-2) + x fp32->fp16 conversion ----------------
__global__ void gate_convert_kernel(const float* __restrict__ x, const float* __restrict__ Wg,
                                    f16* __restrict__ xh, float* __restrict__ gw,
                                    int* __restrict__ gidx, int T) {
    const int tok  = (int)((blockIdx.x * (size_t)blockDim.x + threadIdx.x) >> 6);
    const int lane = threadIdx.x & 63;
    if (tok >= T) return;
    const float4* xr  = (const float4*)(x + (size_t)tok * DIM);
    f16*          xhr = xh + (size_t)tok * DIM;
    float s[NEXP];
    #pragma unroll
    for (int e = 0; e < NEXP; ++e) s[e] = 0.f;
    #pragma unroll
    for (int it = 0; it < 4; ++it) {
        int i = it * 64 + lane;
        float4 xv = xr[i];
        f16x4 hv = { (f16)xv.x, (f16)xv.y, (f16)xv.z, (f16)xv.w };
        *(f16x4*)(xhr + i * 4) = hv;
        #pragma unroll
        for (int e = 0; e < NEXP; ++e) {
            float4 wv = ((const float4*)(Wg + e * DIM))[i];
            s[e] += xv.x * wv.x + xv.y * wv.y + xv.z * wv.z + xv.w * wv.w;
        }
    }
    #pragma unroll
    for (int e = 0; e < NEXP; ++e) {
        #pragma unroll
        for (int off = 32; off > 0; off >>= 1) s[e] += __shfl_xor(s[e], off);
    }
    if (lane == 0) {
        float sc[NEXP];
        #pragma unroll
        for (int e = 0; e < NEXP; ++e) sc[e] = 1.f / (1.f + expf(-s[e]));
        int i0 = 0;
        #pragma unroll
        for (int e = 1; e < NEXP; ++e) if (sc[e] > sc[i0]) i0 = e;
        int i1 = -1;
        #pragma unroll
        for (int e = 0; e < NEXP; ++e) if (e != i0 && (i1 < 0 || sc[e] > sc[i1])) i1 = e;
        float w0 = sc[i0], w1 = sc[i1];
        float inv = 1.f / (w0 + w1);
        gw[2 * tok + 0] = w0 * inv;
        gw[2 * tok + 1] = w1 * inv;
        gidx[2 * tok + 0] = i0;
        gidx[2 * tok + 1] = i1;
    }
}

// ---------------- W[e][K][N] fp32 -> Wt[e][N][K] fp16 — vectorized LDS-tiled transpose ----------------
__global__ void transpose_conv_kernel(const float* __restrict__ W, f16* __restrict__ Wt, int K, int N) {
    __shared__ f16 tile[64][66];
    const int e  = blockIdx.z;
    const int kb = blockIdx.y * 64;
    const int nb = blockIdx.x * 64;
    const int t  = threadIdx.x;
    const float* We  = W  + (size_t)e * K * N;
    f16*         Wte = Wt + (size_t)e * K * N;
    const int kl = t >> 4;          // 0..15
    const int nq = t & 15;          // 0..15 (x4 cols)
    #pragma unroll
    for (int pass = 0; pass < 4; ++pass) {
        int k = pass * 16 + kl;
        float4 v = *(const float4*)&We[(size_t)(kb + k) * N + nb + nq * 4];
        f16x2 lo = { (f16)v.x, (f16)v.y };
        f16x2 hi = { (f16)v.z, (f16)v.w };
        *(f16x2*)&tile[k][nq * 4]     = lo;
        *(f16x2*)&tile[k][nq * 4 + 2] = hi;
    }
    __syncthreads();
    const int n  = t >> 2;          // 0..63
    const int kq = t & 3;           // 0..3 (x16 k)
    f16x8 o0, o1;
    #pragma unroll
    for (int i = 0; i < 8; ++i) o0[i] = tile[kq * 16 + i][n];
    #pragma unroll
    for (int i = 0; i < 8; ++i) o1[i] = tile[kq * 16 + 8 + i][n];
    f16* dst = &Wte[(size_t)(nb + n) * K + kb + kq * 16];
    *(f16x8*)dst       = o0;
    *(f16x8*)(dst + 8) = o1;
}

// ---------------- routing: histogram + scan + rank scatter + compact tile table, one block, no atomics ----------------
__global__ __launch_bounds__(1024)
void route_kernel(const int* __restrict__ gidx, int* __restrict__ offsets,
                  int* __restrict__ tor, int* __restrict__ ros,
                  int* __restrict__ tileE, int* __restrict__ tileR0, int T) {
    const int tid  = threadIdx.x;
    const int lane = tid & 63;
    const int wv   = tid >> 6;
    const int NE   = 2 * T;
    __shared__ int wc[16][NEXP];
    __shared__ int rb[NEXP];

    int c[NEXP];
    #pragma unroll
    for (int e = 0; e < NEXP; ++e) c[e] = 0;
    for (int i = tid; i < NE; i += 1024) {
        int g = gidx[i];
        #pragma unroll
        for (int e = 0; e < NEXP; ++e) c[e] += (g == e) ? 1 : 0;
    }
    #pragma unroll
    for (int e = 0; e < NEXP; ++e) {
        #pragma unroll
        for (int off = 32; off > 0; off >>= 1) c[e] += __shfl_xor(c[e], off);
    }
    if (lane == 0) {
        #pragma unroll
        for (int e = 0; e < NEXP; ++e) wc[wv][e] = c[e];
    }
    __syncthreads();
    if (tid == 0) {
        int acc = 0;
        for (int e = 0; e < NEXP; ++e) {
            int t = 0;
            for (int w2 = 0; w2 < 16; ++w2) t += wc[w2][e];
            offsets[e] = acc;
            rb[e] = acc;
            acc += t;
        }
        offsets[NEXP] = acc;
        int nt = 0;
        for (int e = 0; e < NEXP; ++e)
            for (int r0 = offsets[e]; r0 < offsets[e + 1]; r0 += 128) {
                tileE[nt]  = e;
                tileR0[nt] = r0;
                ++nt;
            }
        for (; nt < TIMAX; ++nt) { tileE[nt] = -1; tileR0[nt] = 0; }
    }
    __syncthreads();

    for (int base = 0; base < NE; base += 1024) {
        int i = base + tid;
        int g = gidx[i];
        int myrank = 0;
        #pragma unroll
        for (int e = 0; e < NEXP; ++e) {
            unsigned long long m = __ballot(g == e);
            if (g == e) myrank = __popcll(m & ((1ull << lane) - 1ull));
            if (lane == 0) wc[wv][e] = __popcll(m);
        }
        __syncthreads();
        int pre = 0;
        for (int w2 = 0; w2 < wv; ++w2) pre += wc[w2][g];
        int pos = rb[g] + pre + myrank;
        tor[pos] = i >> 1;
        ros[i]   = pos;
        __syncthreads();
        if (tid < NEXP) {
            int t = 0;
            for (int w2 = 0; w2 < 16; ++w2) t += wc[w2][tid];
            rb[tid] += t;
        }
        __syncthreads();
    }
}

// ---------------- grouped GEMM: 128x128 tile, 4 waves, BK=64 single-buffered, LATENCY-OVERLAP loop ----------------
// Same 32 KiB single-buffer geometry as R10/R11, but the K-step is re-sequenced with
// raw s_barrier + explicit waits so the stage's HBM/L2 latency hides under MFMA:
//   ds_read x32 (ALL frags) -> lgkmcnt(0) -> s_barrier   [reads done; overwrite safe]
//   stage(kt+1) issue (8 gload16)                        [latency starts ticking]
//   MFMA x64 (frags in regs)                             [covers the latency]
//   vmcnt(0) -> s_barrier                                [next tile landed]
// __syncthreads is NOT used in-loop (its compiler-emitted vmcnt(0) drain at the
// TOP of the step was the exposed-latency bug). Hazards: rule-18 (MFMA hoisting)
// is harmless here - MFMA order is pure dataflow; memory ops are fenced by the
// asm "memory" clobbers + barriers. Swizzle & banding identical to R10 (proven
// 0-conflict / fetch-cut). VGPR rises to ~150 (16 frags live at the barrier) ->
// 3 waves/SIMD, m97's own operating point.
template<int KD, int ND, bool RELU, bool GATHER>
__global__ __launch_bounds__(256)
void moe_gemm_kernel(const f16* __restrict__ Abase, const f16* __restrict__ Bt,
                     const float* __restrict__ bias, const int* __restrict__ offsets,
                     const int* __restrict__ tok, const int* __restrict__ tileE,
                     const int* __restrict__ tileR0, f16* __restrict__ Cout) {
    constexpr int NT  = ND / 128;
    constexpr int NT2 = NT / 2;
    const int bid = blockIdx.x;
    const int xcd = bid & 7;
    const int j   = bid >> 3;
    const int nt  = (j % NT2) * 2 + (xcd & 1);
    const int tih = j / NT2;
    const int ti  = tih * 4 + (xcd >> 1);

    const int e = tileE[ti];
    if (e < 0) return;
    const int row0   = tileR0[ti];
    const int rowEnd = offsets[e + 1];
    const int n0   = nt * 128;
    const int tid  = threadIdx.x;
    const int lane = tid & 63;
    const int wid  = tid >> 6;
    const int wr   = (wid >> 1) * 64;
    const int wc   = (wid & 1) * 64;

    __shared__ __align__(16) f16 As[128 * 64];
    __shared__ __align__(16) f16 Bs[128 * 64];

    const f16* Bte = Bt + (size_t)e * ND * KD;

    // staging: chunk c = i*256+tid (i<4); row r = c>>3, slot = c&7, kc = slot^(r&7)
    int aOff[4], bOff[4], ldsOff[4];
    #pragma unroll
    for (int i = 0; i < 4; ++i) {
        int c  = i * 256 + tid;
        int r  = c >> 3;
        int kc = (c & 7) ^ (r & 7);
        ldsOff[i] = c * 8;
        int gr = row0 + r;
        if (gr >= rowEnd) gr = rowEnd - 1;
        int ar = GATHER ? tok[gr] : gr;
        aOff[i] = ar * KD + kc * 8;
        bOff[i] = (n0 + r) * KD + kc * 8;
    }

    auto stage = [&](int kt) {
        const int k0 = kt * 64;
        #pragma unroll
        for (int i = 0; i < 4; ++i)
            gload16(Abase + (size_t)(aOff[i] + k0), &As[ldsOff[i]]);
        #pragma unroll
        for (int i = 0; i < 4; ++i)
            gload16(Bte + (size_t)(bOff[i] + k0), &Bs[ldsOff[i]]);
    };

    f32x4 acc[4][4] = {};

    const int rb    = lane & 15;
    const int jbase = lane >> 4;     // 0..3

    constexpr int nK = KD / 64;
    stage(0);
    asm volatile("s_waitcnt vmcnt(0)" ::: "memory");
    __builtin_amdgcn_s_barrier();

    for (int kt = 0; kt < nK; ++kt) {
        // --- read ALL fragments of the current tile into registers ---
        f16x8 af[2][4], bfr[2][4];
        #pragma unroll
        for (int ks = 0; ks < 2; ++ks) {
            const int sl = (((ks * 4 + jbase) ^ (rb & 7))) * 8;
            #pragma unroll
            for (int m = 0; m < 4; ++m)
                af[ks][m] = *(const f16x8*)&As[(wr + m * 16 + rb) * 64 + sl];
            #pragma unroll
            for (int n = 0; n < 4; ++n)
                bfr[ks][n] = *(const f16x8*)&Bs[(wc + n * 16 + rb) * 64 + sl];
        }
        asm volatile("s_waitcnt lgkmcnt(0)" ::: "memory");   // my reads complete
        __builtin_amdgcn_s_barrier();                        // everyone's reads complete
        if (kt + 1 < nK) stage(kt + 1);                      // overwrite now safe; latency ticks under MFMA

        #pragma unroll
        for (int ks = 0; ks < 2; ++ks)
            #pragma unroll
            for (int m = 0; m < 4; ++m)
                #pragma unroll
                for (int n = 0; n < 4; ++n)
                    acc[m][n] = __builtin_amdgcn_mfma_f32_16x16x32_f16(
                        af[ks][m], bfr[ks][n], acc[m][n], 0, 0, 0);

        asm volatile("s_waitcnt vmcnt(0)" ::: "memory");     // next tile landed
        __builtin_amdgcn_s_barrier();                        // visible to all waves
    }

    const int rowsValid = rowEnd - row0;
    #pragma unroll
    for (int m = 0; m < 4; ++m) {
        #pragma unroll
        for (int n = 0; n < 4; ++n) {
            #pragma unroll
            for (int j2 = 0; j2 < 4; ++j2) {
                int rl  = wr + m * 16 + ((lane >> 4) << 2) + j2;
                int col = n0 + wc + n * 16 + (lane & 15);
                if (rl < rowsValid) {
                    float v = acc[m][n][j2] + bias[e * ND + col];
                    if (RELU) v = fmaxf(v, 0.f);
                    Cout[(size_t)(row0 + rl) * ND + col] = (f16)v;
                }
            }
        }
    }
}

// ---------------- combine: y[t] = w0*eo[r0] + w1*eo[r1] ----------------
__global__ void combine_kernel(const f16* __restrict__ eo, const int* __restrict__ ros,
                               const float* __restrict__ gw, float* __restrict__ y, int T) {
    int gid = blockIdx.x * 256 + threadIdx.x;
    int t   = gid >> 7;
    if (t >= T) return;
    int c0 = (gid & 127) * 8;
    int r0 = ros[2 * t], r1 = ros[2 * t + 1];
    float w0 = gw[2 * t], w1 = gw[2 * t + 1];
    f16x8 v0 = *(const f16x8*)(eo + (size_t)r0 * DIM + c0);
    f16x8 v1 = *(const f16x8*)(eo + (size_t)r1 * DIM + c0);
    f32x4 o0, o1;
    #pragma unroll
    for (int j = 0; j < 4; ++j) o0[j] = w0 * (float)v0[j] + w1 * (float)v1[j];
    #pragma unroll
    for (int j = 0; j < 4; ++j) o1[j] = w0 * (float)v0[4 + j] + w1 * (float)v1[4 + j];
    *(f32x4*)(y + (size_t)t * DIM + c0)     = o0;
    *(f32x4*)(y + (size_t)t * DIM + c0 + 4) = o1;
}

extern "C" void kernel_launch(void* const* d_in, const int* in_sizes, int n_in,
                              void* d_out, int out_size, void* d_ws, size_t ws_size,
                              hipStream_t stream) {
    const float* x  = (const float*)d_in[0];
    const float* Wg = (const float*)d_in[1];
    const float* W1 = (const float*)d_in[2];
    const float* b1 = (const float*)d_in[3];
    const float* W2 = (const float*)d_in[4];
    const float* b2 = (const float*)d_in[5];
    float* y = (float*)d_out;
    const int T = in_sizes[0] / DIM;   // 8192

    char* ws = (char*)d_ws;
    size_t off = 0;
    auto alloc = [&](size_t bytes) -> char* {
        char* p = ws + off;
        off += (bytes + 255) & ~(size_t)255;
        return p;
    };
    f16* xh   = (f16*)alloc((size_t)T * DIM * 2);
    f16* w1t  = (f16*)alloc((size_t)NEXP * DIM * INTER * 2);
    f16* w2t  = (f16*)alloc((size_t)NEXP * DIM * INTER * 2);
    f16* h    = (f16*)alloc((size_t)2 * T * INTER * 2);
    f16* eo   = (f16*)alloc((size_t)2 * T * DIM * 2);
    float* gw = (float*)alloc((size_t)T * 2 * 4);
    int* gidx = (int*)alloc((size_t)T * 2 * 4);
    int* ros  = (int*)alloc((size_t)T * 2 * 4);
    int* tor  = (int*)alloc((size_t)2 * T * 4);
    int* offsets = (int*)alloc(64 * 4);
    int* tileE   = (int*)alloc(TIMAX * 4);
    int* tileR0  = (int*)alloc(TIMAX * 4);

    gate_convert_kernel<<<T / 4, 256, 0, stream>>>(x, Wg, xh, gw, gidx, T);
    transpose_conv_kernel<<<dim3(INTER / 64, DIM / 64, NEXP), 256, 0, stream>>>(W1, w1t, DIM, INTER);
    transpose_conv_kernel<<<dim3(DIM / 64, INTER / 64, NEXP), 256, 0, stream>>>(W2, w2t, INTER, DIM);
    route_kernel<<<1, 1024, 0, stream>>>(gidx, offsets, tor, ros, tileE, tileR0, T);
    moe_gemm_kernel<DIM, INTER, true, true>
        <<<dim3((TIMAX / 4) * ((INTER / 128) / 2) * 8), 256, 0, stream>>>(xh, w1t, b1, offsets, tor, tileE, tileR0, h);
    moe_gemm_kernel<INTER, DIM, false, false>
        <<<dim3((TIMAX / 4) * ((DIM / 128) / 2) * 8), 256, 0, stream>>>(h, w2t, b2, offsets, tor, tileE, tileR0, eo);
    combine_kernel<<<(T * DIM / 8 + 255) / 256, 256, 0, stream>>>(eo, ros, gw, y, T);
}

// Round 13
// 375.368 us; speedup vs baseline: 1.0391x; 1.0391x over previous
//
#include <hip/hip_runtime.h>
#include <stdint.h>

#define DIM   1024
#define INTER 2048
#define NEXP  8
#define TIMAX 136   // max active 128-row tiles

typedef _Float16 f16;
typedef __attribute__((ext_vector_type(2))) _Float16 f16x2;
typedef __attribute__((ext_vector_type(4))) _Float16 f16x4;
typedef __attribute__((ext_vector_type(8))) _Float16 f16x8;
typedef __attribute__((ext_vector_type(4))) float    f32x4;

// ---------------- async global->LDS (16B per lane) ----------------
static __device__ __forceinline__ void gload16(const void* gsrc, void* lds) {
    __builtin_amdgcn_global_load_lds(
        (const __attribute__((address_space(1))) uint32_t*)gsrc,
        (__attribute__((address_space(3))) uint32_t*)lds,
        16, 0, 0);
}

// ---------------- fused preprocess: gate (sigmoid top-2) + x conversion + BOTH weight transposes ----------------
// One flat grid; block ranges do independent BW-bound work concurrently:
//   [0, T/4)                : gate+convert (1 wave per token, float4 loads)
//   [T/4, T/4+4096)         : W1 [e][K=DIM][N=INTER] -> w1t [e][N][K]
//   [T/4+4096, T/4+8192)    : W2 [e][K=INTER][N=DIM] -> w2t [e][N][K]
__device__ __forceinline__ void transpose_tile(const float* __restrict__ W, f16* __restrict__ Wt,
                                               int K, int N, int e, int kb, int nb, int t,
                                               f16 (*tile)[66]) {
    const float* We  = W  + (size_t)e * K * N;
    f16*         Wte = Wt + (size_t)e * K * N;
    const int kl = t >> 4;          // 0..15
    const int nq = t & 15;          // 0..15 (x4 cols)
    #pragma unroll
    for (int pass = 0; pass < 4; ++pass) {
        int k = pass * 16 + kl;
        float4 v = *(const float4*)&We[(size_t)(kb + k) * N + nb + nq * 4];
        f16x2 lo = { (f16)v.x, (f16)v.y };
        f16x2 hi = { (f16)v.z, (f16)v.w };
        *(f16x2*)&tile[k][nq * 4]     = lo;
        *(f16x2*)&tile[k][nq * 4 + 2] = hi;
    }
    __syncthreads();
    const int n  = t >> 2;          // 0..63
    const int kq = t & 3;           // 0..3 (x16 k)
    f16x8 o0, o1;
    #pragma unroll
    for (int i = 0; i < 8; ++i) o0[i] = tile[kq * 16 + i][n];
    #pragma unroll
    for (int i = 0; i < 8; ++i) o1[i] = tile[kq * 16 + 8 + i][n];
    f16* dst = &Wte[(size_t)(nb + n) * K + kb + kq * 16];
    *(f16x8*)dst       = o0;
    *(f16x8*)(dst + 8) = o1;
}

__global__ void preprocess_kernel(const float* __restrict__ x, const float* __restrict__ Wg,
                                  const float* __restrict__ W1, const float* __restrict__ W2,
                                  f16* __restrict__ xh, f16* __restrict__ w1t, f16* __restrict__ w2t,
                                  float* __restrict__ gw, int* __restrict__ gidx, int T) {
    __shared__ f16 tile[64][66];
    const int bid     = blockIdx.x;
    const int NB_GATE = T / 4;
    const int NB_TR1  = (INTER / 64) * (DIM / 64) * NEXP;   // 4096

    if (bid < NB_GATE) {
        const int tid  = threadIdx.x;
        const int tok  = bid * 4 + (tid >> 6);
        const int lane = tid & 63;
        const float4* xr  = (const float4*)(x + (size_t)tok * DIM);
        f16*          xhr = xh + (size_t)tok * DIM;
        float s[NEXP];
        #pragma unroll
        for (int e = 0; e < NEXP; ++e) s[e] = 0.f;
        #pragma unroll
        for (int it = 0; it < 4; ++it) {
            int i = it * 64 + lane;
            float4 xv = xr[i];
            f16x4 hv = { (f16)xv.x, (f16)xv.y, (f16)xv.z, (f16)xv.w };
            *(f16x4*)(xhr + i * 4) = hv;
            #pragma unroll
            for (int e = 0; e < NEXP; ++e) {
                float4 wv = ((const float4*)(Wg + e * DIM))[i];
                s[e] += xv.x * wv.x + xv.y * wv.y + xv.z * wv.z + xv.w * wv.w;
            }
        }
        #pragma unroll
        for (int e = 0; e < NEXP; ++e) {
            #pragma unroll
            for (int off = 32; off > 0; off >>= 1) s[e] += __shfl_xor(s[e], off);
        }
        if (lane == 0) {
            float sc[NEXP];
            #pragma unroll
            for (int e = 0; e < NEXP; ++e) sc[e] = 1.f / (1.f + expf(-s[e]));
            int i0 = 0;
            #pragma unroll
            for (int e = 1; e < NEXP; ++e) if (sc[e] > sc[i0]) i0 = e;
            int i1 = -1;
            #pragma unroll
            for (int e = 0; e < NEXP; ++e) if (e != i0 && (i1 < 0 || sc[e] > sc[i1])) i1 = e;
            float w0 = sc[i0], w1 = sc[i1];
            float inv = 1.f / (w0 + w1);
            gw[2 * tok + 0] = w0 * inv;
            gw[2 * tok + 1] = w1 * inv;
            gidx[2 * tok + 0] = i0;
            gidx[2 * tok + 1] = i1;
        }
    } else if (bid < NB_GATE + NB_TR1) {
        const int b  = bid - NB_GATE;
        const int nx = b % (INTER / 64);
        const int ky = (b / (INTER / 64)) % (DIM / 64);
        const int e  = b / ((INTER / 64) * (DIM / 64));
        transpose_tile(W1, w1t, DIM, INTER, e, ky * 64, nx * 64, threadIdx.x, tile);
    } else {
        const int b  = bid - NB_GATE - NB_TR1;
        const int nx = b % (DIM / 64);
        const int ky = (b / (DIM / 64)) % (INTER / 64);
        const int e  = b / ((DIM / 64) * (INTER / 64));
        transpose_tile(W2, w2t, INTER, DIM, e, ky * 64, nx * 64, threadIdx.x, tile);
    }
}

// ---------------- routing: histogram + scan + rank scatter (tor, gwp) + compact tile table ----------------
__global__ __launch_bounds__(1024)
void route_kernel(const int* __restrict__ gidx, const float* __restrict__ gw,
                  int* __restrict__ offsets, int* __restrict__ tor, float* __restrict__ gwp,
                  int* __restrict__ tileE, int* __restrict__ tileR0, int T) {
    const int tid  = threadIdx.x;
    const int lane = tid & 63;
    const int wv   = tid >> 6;
    const int NE   = 2 * T;
    __shared__ int wc[16][NEXP];
    __shared__ int rb[NEXP];

    int c[NEXP];
    #pragma unroll
    for (int e = 0; e < NEXP; ++e) c[e] = 0;
    for (int i = tid; i < NE; i += 1024) {
        int g = gidx[i];
        #pragma unroll
        for (int e = 0; e < NEXP; ++e) c[e] += (g == e) ? 1 : 0;
    }
    #pragma unroll
    for (int e = 0; e < NEXP; ++e) {
        #pragma unroll
        for (int off = 32; off > 0; off >>= 1) c[e] += __shfl_xor(c[e], off);
    }
    if (lane == 0) {
        #pragma unroll
        for (int e = 0; e < NEXP; ++e) wc[wv][e] = c[e];
    }
    __syncthreads();
    if (tid == 0) {
        int acc = 0;
        for (int e = 0; e < NEXP; ++e) {
            int t = 0;
            for (int w2 = 0; w2 < 16; ++w2) t += wc[w2][e];
            offsets[e] = acc;
            rb[e] = acc;
            acc += t;
        }
        offsets[NEXP] = acc;
        int nt = 0;
        for (int e = 0; e < NEXP; ++e)
            for (int r0 = offsets[e]; r0 < offsets[e + 1]; r0 += 128) {
                tileE[nt]  = e;
                tileR0[nt] = r0;
                ++nt;
            }
        for (; nt < TIMAX; ++nt) { tileE[nt] = -1; tileR0[nt] = 0; }
    }
    __syncthreads();

    for (int base = 0; base < NE; base += 1024) {
        int i = base + tid;
        int g = gidx[i];
        int myrank = 0;
        #pragma unroll
        for (int e = 0; e < NEXP; ++e) {
            unsigned long long m = __ballot(g == e);
            if (g == e) myrank = __popcll(m & ((1ull << lane) - 1ull));
            if (lane == 0) wc[wv][e] = __popcll(m);
        }
        __syncthreads();
        int pre = 0;
        for (int w2 = 0; w2 < wv; ++w2) pre += wc[w2][g];
        int pos = rb[g] + pre + myrank;
        tor[pos] = i >> 1;
        gwp[pos] = gw[i];
        __syncthreads();
        if (tid < NEXP) {
            int t = 0;
            for (int w2 = 0; w2 < 16; ++w2) t += wc[w2][tid];
            rb[tid] += t;
        }
        __syncthreads();
    }
}

// ---------------- grouped GEMM: 128x128 tile, 4 waves, BK=64 single-buffered loop (R10 core, proven best) ----------------
// ATOMIC=true (GEMM2): epilogue computes (acc+bias)*gwp[row] and atomicAdd's into
// y[token][col] — deterministic: y zero-init, exactly 2 commutative fp32 adds per
// element ((0+x)+y == (0+y)+x bitwise). Eliminates the combine pass + eo buffer.
template<int KD, int ND, bool RELU, bool GATHER, bool ATOMIC>
__global__ __launch_bounds__(256)
void moe_gemm_kernel(const f16* __restrict__ Abase, const f16* __restrict__ Bt,
                     const float* __restrict__ bias, const int* __restrict__ offsets,
                     const int* __restrict__ tok, const int* __restrict__ tileE,
                     const int* __restrict__ tileR0, const float* __restrict__ gwp,
                     float* __restrict__ yout, f16* __restrict__ Cout) {
    constexpr int NT  = ND / 128;
    constexpr int NT2 = NT / 2;
    const int bid = blockIdx.x;
    const int xcd = bid & 7;
    const int j   = bid >> 3;
    const int nt  = (j % NT2) * 2 + (xcd & 1);
    const int tih = j / NT2;
    const int ti  = tih * 4 + (xcd >> 1);

    const int e = tileE[ti];
    if (e < 0) return;
    const int row0   = tileR0[ti];
    const int rowEnd = offsets[e + 1];
    const int n0   = nt * 128;
    const int tid  = threadIdx.x;
    const int lane = tid & 63;
    const int wid  = tid >> 6;
    const int wr   = (wid >> 1) * 64;
    const int wc   = (wid & 1) * 64;

    __shared__ __align__(16) f16 As[128 * 64];
    __shared__ __align__(16) f16 Bs[128 * 64];

    const f16* Bte = Bt + (size_t)e * ND * KD;

    // staging: chunk c = i*256+tid (i<4); row r = c>>3, slot = c&7, kc = slot^(r&7)
    int aOff[4], bOff[4], ldsOff[4];
    #pragma unroll
    for (int i = 0; i < 4; ++i) {
        int c  = i * 256 + tid;
        int r  = c >> 3;
        int kc = (c & 7) ^ (r & 7);
        ldsOff[i] = c * 8;
        int gr = row0 + r;
        if (gr >= rowEnd) gr = rowEnd - 1;
        int ar = GATHER ? tok[gr] : gr;
        aOff[i] = ar * KD + kc * 8;
        bOff[i] = (n0 + r) * KD + kc * 8;
    }

    f32x4 acc[4][4] = {};

    const int rb    = lane & 15;
    const int jbase = lane >> 4;     // 0..3

    constexpr int nK = KD / 64;
    for (int kt = 0; kt < nK; ++kt) {
        const int k0 = kt * 64;
        #pragma unroll
        for (int i = 0; i < 4; ++i)
            gload16(Abase + (size_t)(aOff[i] + k0), &As[ldsOff[i]]);
        #pragma unroll
        for (int i = 0; i < 4; ++i)
            gload16(Bte + (size_t)(bOff[i] + k0), &Bs[ldsOff[i]]);
        __syncthreads();                       // drains vmcnt: tile ready

        #pragma unroll
        for (int ks = 0; ks < 2; ++ks) {
            const int sl = (((ks * 4 + jbase) ^ (rb & 7))) * 8;
            f16x8 af[4], bfr[4];
            #pragma unroll
            for (int m = 0; m < 4; ++m)
                af[m] = *(const f16x8*)&As[(wr + m * 16 + rb) * 64 + sl];
            #pragma unroll
            for (int n = 0; n < 4; ++n)
                bfr[n] = *(const f16x8*)&Bs[(wc + n * 16 + rb) * 64 + sl];
            #pragma unroll
            for (int m = 0; m < 4; ++m)
                #pragma unroll
                for (int n = 0; n < 4; ++n)
                    acc[m][n] = __builtin_amdgcn_mfma_f32_16x16x32_f16(af[m], bfr[n], acc[m][n], 0, 0, 0);
        }

        __syncthreads();                       // all reads done before next stage overwrites
    }

    const int rowsValid = rowEnd - row0;
    #pragma unroll
    for (int m = 0; m < 4; ++m) {
        #pragma unroll
        for (int n = 0; n < 4; ++n) {
            #pragma unroll
            for (int j2 = 0; j2 < 4; ++j2) {
                int rl  = wr + m * 16 + ((lane >> 4) << 2) + j2;
                int col = n0 + wc + n * 16 + (lane & 15);
                if (rl < rowsValid) {
                    int grow = row0 + rl;
                    float v = acc[m][n][j2] + bias[e * ND + col];
                    if (RELU) v = fmaxf(v, 0.f);
                    if (ATOMIC) {
                        atomicAdd(&yout[(size_t)tok[grow] * ND + col], v * gwp[grow]);
                    } else {
                        Cout[(size_t)grow * ND + col] = (f16)v;
                    }
                }
            }
        }
    }
}

extern "C" void kernel_launch(void* const* d_in, const int* in_sizes, int n_in,
                              void* d_out, int out_size, void* d_ws, size_t ws_size,
                              hipStream_t stream) {
    const float* x  = (const float*)d_in[0];
    const float* Wg = (const float*)d_in[1];
    const float* W1 = (const float*)d_in[2];
    const float* b1 = (const float*)d_in[3];
    const float* W2 = (const float*)d_in[4];
    const float* b2 = (const float*)d_in[5];
    float* y = (float*)d_out;
    const int T = in_sizes[0] / DIM;   // 8192

    char* ws = (char*)d_ws;
    size_t off = 0;
    auto alloc = [&](size_t bytes) -> char* {
        char* p = ws + off;
        off += (bytes + 255) & ~(size_t)255;
        return p;
    };
    f16* xh   = (f16*)alloc((size_t)T * DIM * 2);
    f16* w1t  = (f16*)alloc((size_t)NEXP * DIM * INTER * 2);
    f16* w2t  = (f16*)alloc((size_t)NEXP * DIM * INTER * 2);
    f16* h    = (f16*)alloc((size_t)2 * T * INTER * 2);
    float* gw = (float*)alloc((size_t)T * 2 * 4);
    float* gwp= (float*)alloc((size_t)T * 2 * 4);
    int* gidx = (int*)alloc((size_t)T * 2 * 4);
    int* tor  = (int*)alloc((size_t)2 * T * 4);
    int* offsets = (int*)alloc(64 * 4);
    int* tileE   = (int*)alloc(TIMAX * 4);
    int* tileR0  = (int*)alloc(TIMAX * 4);

    hipMemsetAsync(y, 0, (size_t)T * DIM * 4, stream);

    const int NB_GATE = T / 4;
    const int NB_TR1  = (INTER / 64) * (DIM / 64) * NEXP;
    const int NB_TR2  = (DIM / 64) * (INTER / 64) * NEXP;
    preprocess_kernel<<<NB_GATE + NB_TR1 + NB_TR2, 256, 0, stream>>>(
        x, Wg, W1, W2, xh, w1t, w2t, gw, gidx, T);
    route_kernel<<<1, 1024, 0, stream>>>(gidx, gw, offsets, tor, gwp, tileE, tileR0, T);
    moe_gemm_kernel<DIM, INTER, true, true, false>
        <<<dim3((TIMAX / 4) * ((INTER / 128) / 2) * 8), 256, 0, stream>>>(
            xh, w1t, b1, offsets, tor, tileE, tileR0, nullptr, nullptr, h);
    moe_gemm_kernel<INTER, DIM, false, false, true>
        <<<dim3((TIMAX / 4) * ((DIM / 128) / 2) * 8), 256, 0, stream>>>(
            h, w2t, b2, offsets, tor, tileE, tileR0, gwp, y, nullptr);
}

// Round 14
// 319.158 us; speedup vs baseline: 1.2221x; 1.1761x over previous
//
#include <hip/hip_runtime.h>
#include <stdint.h>

#define DIM   1024
#define INTER 2048
#define NEXP  8
#define TIMAX 136   // max active 128-row tiles

typedef _Float16 f16;
typedef __attribute__((ext_vector_type(2))) _Float16 f16x2;
typedef __attribute__((ext_vector_type(4))) _Float16 f16x4;
typedef __attribute__((ext_vector_type(8))) _Float16 f16x8;
typedef __attribute__((ext_vector_type(4))) float    f32x4;

// ---------------- async global->LDS (16B per lane) ----------------
static __device__ __forceinline__ void gload16(const void* gsrc, void* lds) {
    __builtin_amdgcn_global_load_lds(
        (const __attribute__((address_space(1))) uint32_t*)gsrc,
        (__attribute__((address_space(3))) uint32_t*)lds,
        16, 0, 0);
}

// ---------------- fused preprocess: gate (sigmoid top-2) + x conversion + BOTH weight transposes ----------------
__device__ __forceinline__ void transpose_tile(const float* __restrict__ W, f16* __restrict__ Wt,
                                               int K, int N, int e, int kb, int nb, int t,
                                               f16 (*tile)[66]) {
    const float* We  = W  + (size_t)e * K * N;
    f16*         Wte = Wt + (size_t)e * K * N;
    const int kl = t >> 4;          // 0..15
    const int nq = t & 15;          // 0..15 (x4 cols)
    #pragma unroll
    for (int pass = 0; pass < 4; ++pass) {
        int k = pass * 16 + kl;
        float4 v = *(const float4*)&We[(size_t)(kb + k) * N + nb + nq * 4];
        f16x2 lo = { (f16)v.x, (f16)v.y };
        f16x2 hi = { (f16)v.z, (f16)v.w };
        *(f16x2*)&tile[k][nq * 4]     = lo;
        *(f16x2*)&tile[k][nq * 4 + 2] = hi;
    }
    __syncthreads();
    const int n  = t >> 2;          // 0..63
    const int kq = t & 3;           // 0..3 (x16 k)
    f16x8 o0, o1;
    #pragma unroll
    for (int i = 0; i < 8; ++i) o0[i] = tile[kq * 16 + i][n];
    #pragma unroll
    for (int i = 0; i < 8; ++i) o1[i] = tile[kq * 16 + 8 + i][n];
    f16* dst = &Wte[(size_t)(nb + n) * K + kb + kq * 16];
    *(f16x8*)dst       = o0;
    *(f16x8*)(dst + 8) = o1;
}

__global__ void preprocess_kernel(const float* __restrict__ x, const float* __restrict__ Wg,
                                  const float* __restrict__ W1, const float* __restrict__ W2,
                                  f16* __restrict__ xh, f16* __restrict__ w1t, f16* __restrict__ w2t,
                                  float* __restrict__ gw, int* __restrict__ gidx, int T) {
    __shared__ f16 tile[64][66];
    const int bid     = blockIdx.x;
    const int NB_GATE = T / 4;
    const int NB_TR1  = (INTER / 64) * (DIM / 64) * NEXP;   // 4096

    if (bid < NB_GATE) {
        const int tid  = threadIdx.x;
        const int tok  = bid * 4 + (tid >> 6);
        const int lane = tid & 63;
        const float4* xr  = (const float4*)(x + (size_t)tok * DIM);
        f16*          xhr = xh + (size_t)tok * DIM;
        float s[NEXP];
        #pragma unroll
        for (int e = 0; e < NEXP; ++e) s[e] = 0.f;
        #pragma unroll
        for (int it = 0; it < 4; ++it) {
            int i = it * 64 + lane;
            float4 xv = xr[i];
            f16x4 hv = { (f16)xv.x, (f16)xv.y, (f16)xv.z, (f16)xv.w };
            *(f16x4*)(xhr + i * 4) = hv;
            #pragma unroll
            for (int e = 0; e < NEXP; ++e) {
                float4 wv = ((const float4*)(Wg + e * DIM))[i];
                s[e] += xv.x * wv.x + xv.y * wv.y + xv.z * wv.z + xv.w * wv.w;
            }
        }
        #pragma unroll
        for (int e = 0; e < NEXP; ++e) {
            #pragma unroll
            for (int off = 32; off > 0; off >>= 1) s[e] += __shfl_xor(s[e], off);
        }
        if (lane == 0) {
            float sc[NEXP];
            #pragma unroll
            for (int e = 0; e < NEXP; ++e) sc[e] = 1.f / (1.f + expf(-s[e]));
            int i0 = 0;
            #pragma unroll
            for (int e = 1; e < NEXP; ++e) if (sc[e] > sc[i0]) i0 = e;
            int i1 = -1;
            #pragma unroll
            for (int e = 0; e < NEXP; ++e) if (e != i0 && (i1 < 0 || sc[e] > sc[i1])) i1 = e;
            float w0 = sc[i0], w1 = sc[i1];
            float inv = 1.f / (w0 + w1);
            gw[2 * tok + 0] = w0 * inv;
            gw[2 * tok + 1] = w1 * inv;
            gidx[2 * tok + 0] = i0;
            gidx[2 * tok + 1] = i1;
        }
    } else if (bid < NB_GATE + NB_TR1) {
        const int b  = bid - NB_GATE;
        const int nx = b % (INTER / 64);
        const int ky = (b / (INTER / 64)) % (DIM / 64);
        const int e  = b / ((INTER / 64) * (DIM / 64));
        transpose_tile(W1, w1t, DIM, INTER, e, ky * 64, nx * 64, threadIdx.x, tile);
    } else {
        const int b  = bid - NB_GATE - NB_TR1;
        const int nx = b % (DIM / 64);
        const int ky = (b / (DIM / 64)) % (INTER / 64);
        const int e  = b / ((DIM / 64) * (INTER / 64));
        transpose_tile(W2, w2t, INTER, DIM, e, ky * 64, nx * 64, threadIdx.x, tile);
    }
}

// ---------------- routing: histogram + scan + rank scatter + compact tile table, one block, no atomics ----------------
__global__ __launch_bounds__(1024)
void route_kernel(const int* __restrict__ gidx, int* __restrict__ offsets,
                  int* __restrict__ tor, int* __restrict__ ros,
                  int* __restrict__ tileE, int* __restrict__ tileR0, int T) {
    const int tid  = threadIdx.x;
    const int lane = tid & 63;
    const int wv   = tid >> 6;
    const int NE   = 2 * T;
    __shared__ int wc[16][NEXP];
    __shared__ int rb[NEXP];

    int c[NEXP];
    #pragma unroll
    for (int e = 0; e < NEXP; ++e) c[e] = 0;
    for (int i = tid; i < NE; i += 1024) {
        int g = gidx[i];
        #pragma unroll
        for (int e = 0; e < NEXP; ++e) c[e] += (g == e) ? 1 : 0;
    }
    #pragma unroll
    for (int e = 0; e < NEXP; ++e) {
        #pragma unroll
        for (int off = 32; off > 0; off >>= 1) c[e] += __shfl_xor(c[e], off);
    }
    if (lane == 0) {
        #pragma unroll
        for (int e = 0; e < NEXP; ++e) wc[wv][e] = c[e];
    }
    __syncthreads();
    if (tid == 0) {
        int acc = 0;
        for (int e = 0; e < NEXP; ++e) {
            int t = 0;
            for (int w2 = 0; w2 < 16; ++w2) t += wc[w2][e];
            offsets[e] = acc;
            rb[e] = acc;
            acc += t;
        }
        offsets[NEXP] = acc;
        int nt = 0;
        for (int e = 0; e < NEXP; ++e)
            for (int r0 = offsets[e]; r0 < offsets[e + 1]; r0 += 128) {
                tileE[nt]  = e;
                tileR0[nt] = r0;
                ++nt;
            }
        for (; nt < TIMAX; ++nt) { tileE[nt] = -1; tileR0[nt] = 0; }
    }
    __syncthreads();

    for (int base = 0; base < NE; base += 1024) {
        int i = base + tid;
        int g = gidx[i];
        int myrank = 0;
        #pragma unroll
        for (int e = 0; e < NEXP; ++e) {
            unsigned long long m = __ballot(g == e);
            if (g == e) myrank = __popcll(m & ((1ull << lane) - 1ull));
            if (lane == 0) wc[wv][e] = __popcll(m);
        }
        __syncthreads();
        int pre = 0;
        for (int w2 = 0; w2 < wv; ++w2) pre += wc[w2][g];
        int pos = rb[g] + pre + myrank;
        tor[pos] = i >> 1;
        ros[i]   = pos;
        __syncthreads();
        if (tid < NEXP) {
            int t = 0;
            for (int w2 = 0; w2 < 16; ++w2) t += wc[w2][tid];
            rb[tid] += t;
        }
        __syncthreads();
    }
}

// ---------------- grouped GEMM: 128x128 tile, 4 waves, BK=64 single-buffered loop (R10/R11 core, proven best) ----------------
template<int KD, int ND, bool RELU, bool GATHER>
__global__ __launch_bounds__(256)
void moe_gemm_kernel(const f16* __restrict__ Abase, const f16* __restrict__ Bt,
                     const float* __restrict__ bias, const int* __restrict__ offsets,
                     const int* __restrict__ tok, const int* __restrict__ tileE,
                     const int* __restrict__ tileR0, f16* __restrict__ Cout) {
    constexpr int NT  = ND / 128;
    constexpr int NT2 = NT / 2;
    const int bid = blockIdx.x;
    const int xcd = bid & 7;
    const int j   = bid >> 3;
    const int nt  = (j % NT2) * 2 + (xcd & 1);
    const int tih = j / NT2;
    const int ti  = tih * 4 + (xcd >> 1);

    const int e = tileE[ti];
    if (e < 0) return;
    const int row0   = tileR0[ti];
    const int rowEnd = offsets[e + 1];
    const int n0   = nt * 128;
    const int tid  = threadIdx.x;
    const int lane = tid & 63;
    const int wid  = tid >> 6;
    const int wr   = (wid >> 1) * 64;
    const int wc   = (wid & 1) * 64;

    __shared__ __align__(16) f16 As[128 * 64];
    __shared__ __align__(16) f16 Bs[128 * 64];

    const f16* Bte = Bt + (size_t)e * ND * KD;

    // staging: chunk c = i*256+tid (i<4); row r = c>>3, slot = c&7, kc = slot^(r&7)
    int aOff[4], bOff[4], ldsOff[4];
    #pragma unroll
    for (int i = 0; i < 4; ++i) {
        int c  = i * 256 + tid;
        int r  = c >> 3;
        int kc = (c & 7) ^ (r & 7);
        ldsOff[i] = c * 8;
        int gr = row0 + r;
        if (gr >= rowEnd) gr = rowEnd - 1;
        int ar = GATHER ? tok[gr] : gr;
        aOff[i] = ar * KD + kc * 8;
        bOff[i] = (n0 + r) * KD + kc * 8;
    }

    f32x4 acc[4][4] = {};

    const int rb    = lane & 15;
    const int jbase = lane >> 4;     // 0..3

    constexpr int nK = KD / 64;
    for (int kt = 0; kt < nK; ++kt) {
        const int k0 = kt * 64;
        #pragma unroll
        for (int i = 0; i < 4; ++i)
            gload16(Abase + (size_t)(aOff[i] + k0), &As[ldsOff[i]]);
        #pragma unroll
        for (int i = 0; i < 4; ++i)
            gload16(Bte + (size_t)(bOff[i] + k0), &Bs[ldsOff[i]]);
        __syncthreads();                       // drains vmcnt: tile ready

        #pragma unroll
        for (int ks = 0; ks < 2; ++ks) {
            const int sl = (((ks * 4 + jbase) ^ (rb & 7))) * 8;
            f16x8 af[4], bfr[4];
            #pragma unroll
            for (int m = 0; m < 4; ++m)
                af[m] = *(const f16x8*)&As[(wr + m * 16 + rb) * 64 + sl];
            #pragma unroll
            for (int n = 0; n < 4; ++n)
                bfr[n] = *(const f16x8*)&Bs[(wc + n * 16 + rb) * 64 + sl];
            #pragma unroll
            for (int m = 0; m < 4; ++m)
                #pragma unroll
                for (int n = 0; n < 4; ++n)
                    acc[m][n] = __builtin_amdgcn_mfma_f32_16x16x32_f16(af[m], bfr[n], acc[m][n], 0, 0, 0);
        }

        __syncthreads();                       // all reads done before next stage overwrites
    }

    const int rowsValid = rowEnd - row0;
    #pragma unroll
    for (int m = 0; m < 4; ++m) {
        #pragma unroll
        for (int n = 0; n < 4; ++n) {
            #pragma unroll
            for (int j2 = 0; j2 < 4; ++j2) {
                int rl  = wr + m * 16 + ((lane >> 4) << 2) + j2;
                int col = n0 + wc + n * 16 + (lane & 15);
                if (rl < rowsValid) {
                    float v = acc[m][n][j2] + bias[e * ND + col];
                    if (RELU) v = fmaxf(v, 0.f);
                    Cout[(size_t)(row0 + rl) * ND + col] = (f16)v;
                }
            }
        }
    }
}

// ---------------- combine: y[t] = w0*eo[r0] + w1*eo[r1] ----------------
__global__ void combine_kernel(const f16* __restrict__ eo, const int* __restrict__ ros,
                               const float* __restrict__ gw, float* __restrict__ y, int T) {
    int gid = blockIdx.x * 256 + threadIdx.x;
    int t   = gid >> 7;
    if (t >= T) return;
    int c0 = (gid & 127) * 8;
    int r0 = ros[2 * t], r1 = ros[2 * t + 1];
    float w0 = gw[2 * t], w1 = gw[2 * t + 1];
    f16x8 v0 = *(const f16x8*)(eo + (size_t)r0 * DIM + c0);
    f16x8 v1 = *(const f16x8*)(eo + (size_t)r1 * DIM + c0);
    f32x4 o0, o1;
    #pragma unroll
    for (int j = 0; j < 4; ++j) o0[j] = w0 * (float)v0[j] + w1 * (float)v1[j];
    #pragma unroll
    for (int j = 0; j < 4; ++j) o1[j] = w0 * (float)v0[4 + j] + w1 * (float)v1[4 + j];
    *(f32x4*)(y + (size_t)t * DIM + c0)     = o0;
    *(f32x4*)(y + (size_t)t * DIM + c0 + 4) = o1;
}

extern "C" void kernel_launch(void* const* d_in, const int* in_sizes, int n_in,
                              void* d_out, int out_size, void* d_ws, size_t ws_size,
                              hipStream_t stream) {
    const float* x  = (const float*)d_in[0];
    const float* Wg = (const float*)d_in[1];
    const float* W1 = (const float*)d_in[2];
    const float* b1 = (const float*)d_in[3];
    const float* W2 = (const float*)d_in[4];
    const float* b2 = (const float*)d_in[5];
    float* y = (float*)d_out;
    const int T = in_sizes[0] / DIM;   // 8192

    char* ws = (char*)d_ws;
    size_t off = 0;
    auto alloc = [&](size_t bytes) -> char* {
        char* p = ws + off;
        off += (bytes + 255) & ~(size_t)255;
        return p;
    };
    f16* xh   = (f16*)alloc((size_t)T * DIM * 2);
    f16* w1t  = (f16*)alloc((size_t)NEXP * DIM * INTER * 2);
    f16* w2t  = (f16*)alloc((size_t)NEXP * DIM * INTER * 2);
    f16* h    = (f16*)alloc((size_t)2 * T * INTER * 2);
    f16* eo   = (f16*)alloc((size_t)2 * T * DIM * 2);
    float* gw = (float*)alloc((size_t)T * 2 * 4);
    int* gidx = (int*)alloc((size_t)T * 2 * 4);
    int* ros  = (int*)alloc((size_t)T * 2 * 4);
    int* tor  = (int*)alloc((size_t)2 * T * 4);
    int* offsets = (int*)alloc(64 * 4);
    int* tileE   = (int*)alloc(TIMAX * 4);
    int* tileR0  = (int*)alloc(TIMAX * 4);

    const int NB_GATE = T / 4;
    const int NB_TR1  = (INTER / 64) * (DIM / 64) * NEXP;
    const int NB_TR2  = (DIM / 64) * (INTER / 64) * NEXP;
    preprocess_kernel<<<NB_GATE + NB_TR1 + NB_TR2, 256, 0, stream>>>(
        x, Wg, W1, W2, xh, w1t, w2t, gw, gidx, T);
    route_kernel<<<1, 1024, 0, stream>>>(gidx, offsets, tor, ros, tileE, tileR0, T);
    moe_gemm_kernel<DIM, INTER, true, true>
        <<<dim3((TIMAX / 4) * ((INTER / 128) / 2) * 8), 256, 0, stream>>>(
            xh, w1t, b1, offsets, tor, tileE, tileR0, h);
    moe_gemm_kernel<INTER, DIM, false, false>
        <<<dim3((TIMAX / 4) * ((DIM / 128) / 2) * 8), 256, 0, stream>>>(
            h, w2t, b2, offsets, tor, tileE, tileR0, eo);
    combine_kernel<<<(T * DIM / 8 + 255) / 256, 256, 0, stream>>>(eo, ros, gw, y, T);
}